// Round 14
// baseline (183.507 us; speedup 1.0000x reference)
//
#include <hip/hip_runtime.h>

#define NF 64      // hidden width (both layers)
#define NBLK 128   // chunks for the two-pass bucket sort
#define MAXNB 2048 // max buckets supported by LDS histograms (n <= 131072)

typedef unsigned short ushort_t;

__device__ inline ushort_t f2bf(float f) {               // RNE f32 -> bf16
    unsigned u = __float_as_uint(f);
    return (ushort_t)((u + 0x7fffu + ((u >> 16) & 1u)) >> 16);
}
__device__ inline float bfhi(unsigned x) { return __uint_as_float(x & 0xffff0000u); }
__device__ inline float bflo(unsigned x) { return __uint_as_float(x << 16); }

// =================== scan utilities ===================

__device__ inline int wave_incl_scan(int x, int lane) {
#pragma unroll
    for (int o = 1; o < 64; o <<= 1) { int y = __shfl_up(x, o, 64); if (lane >= o) x += y; }
    return x;
}

// 1024 elements per block (256 threads x 4); in-place safe
__global__ __launch_bounds__(256) void k_scan_a(const int* __restrict__ in, int* __restrict__ out,
                                                int* __restrict__ bsums, int n) {
    int t = threadIdx.x, lane = t & 63, wv = t >> 6;
    int base = blockIdx.x * 1024 + t * 4;
    int v[4]; int s = 0;
#pragma unroll
    for (int k = 0; k < 4; ++k) { int i = base + k; int x = (i < n) ? in[i] : 0; v[k] = s; s += x; }
    int incl = wave_incl_scan(s, lane);
    __shared__ int ws[4];
    if (lane == 63) ws[wv] = incl;
    __syncthreads();
    int wofs = 0;
#pragma unroll
    for (int w = 0; w < 4; ++w) if (w < wv) wofs += ws[w];
    int texcl = wofs + incl - s;
#pragma unroll
    for (int k = 0; k < 4; ++k) { int i = base + k; if (i < n) out[i] = texcl + v[k]; }
    if (t == 255) bsums[blockIdx.x] = wofs + incl;
}

// single-block exclusive scan over up to 2048 entries; in-place safe
__global__ __launch_bounds__(256) void k_scan_small(const int* __restrict__ cnt, int* __restrict__ ptr, int NB) {
    int t = threadIdx.x, lane = t & 63, wv = t >> 6;
    int base = t * 8;
    int local[8]; int s = 0;
#pragma unroll
    for (int k = 0; k < 8; ++k) { int i = base + k; int x = (i < NB) ? cnt[i] : 0; local[k] = s; s += x; }
    int incl = wave_incl_scan(s, lane);
    __shared__ int ws[4];
    if (lane == 63) ws[wv] = incl;
    __syncthreads();
    int wofs = 0;
#pragma unroll
    for (int w = 0; w < 4; ++w) if (w < wv) wofs += ws[w];
    int texcl = wofs + incl - s;
#pragma unroll
    for (int k = 0; k < 8; ++k) { int i = base + k; if (i < NB) ptr[i] = texcl + local[k]; }
}

// add block sums; also emit bucket pointers (bptr[b] = scanned hmat[b*NBLK], bptr[NB] = E)
__global__ __launch_bounds__(256) void k_scan_addb(int* __restrict__ data, const int* __restrict__ bsums,
                                                   int* __restrict__ bptr, int ntot, int E) {
    int i = blockIdx.x * 256 + threadIdx.x;
    if (i < ntot) {
        int v = data[i] + bsums[i >> 10];
        data[i] = v;
        if ((i & (NBLK - 1)) == 0) bptr[i / NBLK] = v;
    }
    if (i == 0) bptr[ntot / NBLK] = E;
}

// =================== contention-free bucket sort (bucket = dst >> 6) ===================

__global__ __launch_bounds__(256) void k_histA(const int* __restrict__ dst, int* __restrict__ hmat,
                                               int E, int NB, int chunk) {
    __shared__ int h[MAXNB];
    int blk = blockIdx.x;
    for (int i = threadIdx.x; i < NB; i += 256) h[i] = 0;
    __syncthreads();
    int beg = blk * chunk, end = beg + chunk; if (end > E) end = E;
    for (int e = beg + threadIdx.x; e < end; e += 256) atomicAdd(&h[dst[e] >> 6], 1);
    __syncthreads();
    for (int i = threadIdx.x; i < NB; i += 256) hmat[i * NBLK + blk] = h[i];
}

__global__ __launch_bounds__(256) void k_placeB(const int* __restrict__ src, const int* __restrict__ dst,
                                                const int* __restrict__ hmat, int* __restrict__ pairs,
                                                int E, int NB, int chunk) {
    __shared__ int cur[MAXNB];
    int blk = blockIdx.x;
    for (int i = threadIdx.x; i < NB; i += 256) cur[i] = hmat[i * NBLK + blk];
    __syncthreads();
    int beg = blk * chunk, end = beg + chunk; if (end > E) end = E;
    for (int e = beg + threadIdx.x; e < end; e += 256) {
        int s = src[e], d = dst[e];
        int off = atomicAdd(&cur[d >> 6], 1);
        pairs[off] = (s << 6) | (d & 63);
    }
}

// =================== fused node-level CSR: hist + 64-scan + row_ptr/cnt/dinv + place ===================
__global__ __launch_bounds__(256) void k_csr(const int* __restrict__ bptr, const int* __restrict__ pairs,
                                             int* __restrict__ row_ptr, int* __restrict__ cnt,
                                             float* __restrict__ dinv, int* __restrict__ col, int n) {
    __shared__ int h[64];
    __shared__ int cur[64];
    int b = blockIdx.x, t = threadIdx.x;
    if (t < 64) h[t] = 0;
    __syncthreads();
    int beg = bptr[b], end = bptr[b + 1];
    for (int j = beg + t; j < end; j += 256) atomicAdd(&h[pairs[j] & 63], 1);
    __syncthreads();
    if (t < 64) {
        int c = h[t];
        int ex = wave_incl_scan(c, t) - c;
        int node = (b << 6) + t;
        if (node < n) {
            row_ptr[node] = beg + ex;
            cnt[node] = c;
            dinv[node] = rsqrtf(1.0f + (float)c);
        }
        cur[t] = beg + ex;
    }
    __syncthreads();
    for (int j = beg + t; j < end; j += 256) {
        int pk = pairs[j];
        int p = atomicAdd(&cur[pk & 63], 1);
        col[p] = pk >> 6;
    }
}

// =================== GEMM1 (f32 in): K-tiled LDS W (16 KB) + round-11 inner loop ===================
// hs[n][64](bf16) = (X @ W) * dinv[row].  Block: 64 rows x 64 cols. Thread: 4 rows x 4 cols.
// Single f32 path only (round-12 lesson: never co-mingle two load paths -> scratch spill).
template<int K>
__global__ __launch_bounds__(256, 4) void k_gemm(
    const float* __restrict__ X, const float* __restrict__ W,
    const float* __restrict__ dinv, ushort_t* __restrict__ out, int n)
{
    constexpr int KT = 64;                       // k-tile -> 16 KB LDS
    __shared__ float Ws[KT * NF];
    int t = threadIdx.x;
    int c0 = (t & 15) * 4;                       // 16 col-groups x 4 cols
    int row0 = blockIdx.x * 64 + (t >> 4) * 4;   // 16 row-groups x 4 rows

    const float* Xr[4];
#pragma unroll
    for (int r = 0; r < 4; ++r) {
        int row = row0 + r; if (row >= n) row = n - 1;   // clamp: dup loads, stores guarded
        Xr[r] = X + (size_t)row * K;
    }

    float4 acc[4];
#pragma unroll
    for (int r = 0; r < 4; ++r) acc[r] = make_float4(0.f, 0.f, 0.f, 0.f);

    for (int kt = 0; kt < K; kt += KT) {
        if (kt) __syncthreads();                 // drain readers of previous tile
        for (int i = t; i < KT * NF / 4; i += 256)
            ((float4*)Ws)[i] = ((const float4*)(W + (size_t)kt * NF))[i];
        __syncthreads();

#pragma unroll 2
        for (int kb = 0; kb < KT; kb += 16) {
            float4 xv[4][4];                     // 4 rows x 4 k-chunks, all independent loads
#pragma unroll
            for (int r = 0; r < 4; ++r)
#pragma unroll
                for (int q = 0; q < 4; ++q)
                    xv[r][q] = *(const float4*)(Xr[r] + kt + kb + q * 4);

#pragma unroll
            for (int q = 0; q < 4; ++q) {
#pragma unroll
                for (int kk = 0; kk < 4; ++kk) {
                    float4 w = *(const float4*)(&Ws[(kb + q * 4 + kk) * NF + c0]);
#pragma unroll
                    for (int r = 0; r < 4; ++r) {
                        float xs = ((const float*)&xv[r][q])[kk];
                        acc[r].x = fmaf(xs, w.x, acc[r].x);
                        acc[r].y = fmaf(xs, w.y, acc[r].y);
                        acc[r].z = fmaf(xs, w.z, acc[r].z);
                        acc[r].w = fmaf(xs, w.w, acc[r].w);
                    }
                }
            }
        }
    }

#pragma unroll
    for (int r = 0; r < 4; ++r) {
        int row = row0 + r;
        if (row < n) {
            float di = dinv[row];
            ushort4 o;
            o.x = f2bf(acc[r].x * di); o.y = f2bf(acc[r].y * di);
            o.z = f2bf(acc[r].z * di); o.w = f2bf(acc[r].w * di);
            *(ushort4*)(out + (size_t)row * NF + c0) = o;
        }
    }
}

// =================== GEMM2 (bf16 in): LDS W (16 KB), clean direct-member extraction ===================
// hs[n][64](bf16) = (Xb @ W) * dinv[row].  Xb is bf16 [n][64]. Same 64x64 block / 4x4 thread tile.
__global__ __launch_bounds__(256, 4) void k_gemm_bf(
    const ushort_t* __restrict__ Xb, const float* __restrict__ W,
    const float* __restrict__ dinv, ushort_t* __restrict__ out, int n)
{
    constexpr int K = 64;
    __shared__ float Ws[K * NF];                 // 16 KB
    int t = threadIdx.x;
    for (int i = t; i < K * NF / 4; i += 256) ((float4*)Ws)[i] = ((const float4*)W)[i];
    __syncthreads();

    int c0 = (t & 15) * 4;
    int row0 = blockIdx.x * 64 + (t >> 4) * 4;

    const ushort_t* Xr[4];
#pragma unroll
    for (int r = 0; r < 4; ++r) {
        int row = row0 + r; if (row >= n) row = n - 1;   // clamp: dup loads, stores guarded
        Xr[r] = Xb + (size_t)row * K;
    }

    float4 acc[4];
#pragma unroll
    for (int r = 0; r < 4; ++r) acc[r] = make_float4(0.f, 0.f, 0.f, 0.f);

#pragma unroll 2
    for (int kb = 0; kb < K; kb += 16) {
        uint2 xh[4][4];                          // 4 rows x 4 chunks of 4 bf16 (8 B each)
#pragma unroll
        for (int r = 0; r < 4; ++r)
#pragma unroll
            for (int q = 0; q < 4; ++q)
                xh[r][q] = *(const uint2*)(Xr[r] + kb + q * 4);

#pragma unroll
        for (int q = 0; q < 4; ++q) {
            float4 w0 = *(const float4*)(&Ws[(kb + q * 4 + 0) * NF + c0]);
            float4 w1 = *(const float4*)(&Ws[(kb + q * 4 + 1) * NF + c0]);
            float4 w2 = *(const float4*)(&Ws[(kb + q * 4 + 2) * NF + c0]);
            float4 w3 = *(const float4*)(&Ws[(kb + q * 4 + 3) * NF + c0]);
#pragma unroll
            for (int r = 0; r < 4; ++r) {
                float xs0 = bflo(xh[r][q].x);
                float xs1 = bfhi(xh[r][q].x);
                float xs2 = bflo(xh[r][q].y);
                float xs3 = bfhi(xh[r][q].y);
                acc[r].x = fmaf(xs0, w0.x, acc[r].x); acc[r].y = fmaf(xs0, w0.y, acc[r].y);
                acc[r].z = fmaf(xs0, w0.z, acc[r].z); acc[r].w = fmaf(xs0, w0.w, acc[r].w);
                acc[r].x = fmaf(xs1, w1.x, acc[r].x); acc[r].y = fmaf(xs1, w1.y, acc[r].y);
                acc[r].z = fmaf(xs1, w1.z, acc[r].z); acc[r].w = fmaf(xs1, w1.w, acc[r].w);
                acc[r].x = fmaf(xs2, w2.x, acc[r].x); acc[r].y = fmaf(xs2, w2.y, acc[r].y);
                acc[r].z = fmaf(xs2, w2.z, acc[r].z); acc[r].w = fmaf(xs2, w2.w, acc[r].w);
                acc[r].x = fmaf(xs3, w3.x, acc[r].x); acc[r].y = fmaf(xs3, w3.y, acc[r].y);
                acc[r].z = fmaf(xs3, w3.z, acc[r].z); acc[r].w = fmaf(xs3, w3.w, acc[r].w);
            }
        }
    }

#pragma unroll
    for (int r = 0; r < 4; ++r) {
        int row = row0 + r;
        if (row < n) {
            float di = dinv[row];
            ushort4 o;
            o.x = f2bf(acc[r].x * di); o.y = f2bf(acc[r].y * di);
            o.z = f2bf(acc[r].z * di); o.w = f2bf(acc[r].w * di);
            *(ushort4*)(out + (size_t)row * NF + c0) = o;
        }
    }
}

// =================== pull aggregation: one 16-lane group per dst node, bf16 rows ===================
// r = relu( dinv[d] * (hs[d] + sum_{s in N(d)} hs[s]) + bias )
// DECODE=0: write r row as bf16;  DECODE=1: write out[d] = r . Wd + bd (f32 scalar)
template<bool DECODE>
__global__ __launch_bounds__(256) void k_pull(
    const ushort_t* __restrict__ hs, const float* __restrict__ dinv,
    const int* __restrict__ row_ptr, const int* __restrict__ cnt,
    const int* __restrict__ col, const float* __restrict__ bias,
    const float* __restrict__ Wd, const float* __restrict__ bd,
    void* __restrict__ outv, int n)
{
    int d = blockIdx.x * 16 + (threadIdx.x >> 4);
    if (d >= n) return;
    int lt = threadIdx.x & 15;            // lane in group
    int fo = lt << 2;                     // feature offset (4 features/lane)
    int grpbase = threadIdx.x & 48;       // group base lane within wave
    int beg = row_ptr[d], deg = cnt[d];

    // self-loop (bf16 row, 8B/lane)
    uint2 sv = *((const uint2*)(hs + (size_t)d * NF) + lt);
    float4 acc = make_float4(bflo(sv.x), bfhi(sv.x), bflo(sv.y), bfhi(sv.y));

    for (int jb = 0; jb < deg; jb += 16) {
        int m = deg - jb; if (m > 16) m = 16;
        int idx = (lt < m) ? col[beg + jb + lt] : 0;
        uint2 v[16];
#pragma unroll
        for (int u = 0; u < 16; ++u) {
            int kk = (u < m) ? u : (m - 1);                  // clamp: dup loads hit L1
            int s = __shfl(idx, grpbase + kk, 64);
            v[u] = *((const uint2*)(hs + (size_t)s * NF) + lt);
        }
#pragma unroll
        for (int u = 0; u < 16; ++u) {
            if (u < m) {
                acc.x += bflo(v[u].x); acc.y += bfhi(v[u].x);
                acc.z += bflo(v[u].y); acc.w += bfhi(v[u].y);
            }
        }
    }

    float di = dinv[d];
    float4 bv = *(const float4*)(bias + fo);
    float rx = fmaxf(fmaf(acc.x, di, bv.x), 0.0f);
    float ry = fmaxf(fmaf(acc.y, di, bv.y), 0.0f);
    float rz = fmaxf(fmaf(acc.z, di, bv.z), 0.0f);
    float rw = fmaxf(fmaf(acc.w, di, bv.w), 0.0f);

    if (DECODE) {
        float4 wv = *(const float4*)(Wd + fo);
        float vsum = rx * wv.x + ry * wv.y + rz * wv.z + rw * wv.w;
#pragma unroll
        for (int o = 1; o < 16; o <<= 1) vsum += __shfl_xor(vsum, o, 64);
        if (lt == 0) ((float*)outv)[d] = vsum + bd[0];
    } else {
        ushort4 o;
        o.x = f2bf(rx); o.y = f2bf(ry); o.z = f2bf(rz); o.w = f2bf(rw);
        *(ushort4*)((ushort_t*)outv + (size_t)d * NF + fo) = o;
    }
}

extern "C" void kernel_launch(void* const* d_in, const int* in_sizes, int n_in,
                              void* d_out, int out_size, void* d_ws, size_t ws_size,
                              hipStream_t stream) {
    const float* x  = (const float*)d_in[0];
    const int*   ei = (const int*)d_in[1];
    const float* W1 = (const float*)d_in[2];
    const float* b1 = (const float*)d_in[3];
    const float* W2 = (const float*)d_in[4];
    const float* b2 = (const float*)d_in[5];
    const float* Wd = (const float*)d_in[6];
    const float* bd = (const float*)d_in[7];
    float* out = (float*)d_out;

    int n = in_sizes[0] / 128;
    int E = in_sizes[1] / 2;
    const int* src = ei;
    const int* dst = ei + E;

    int NB = (n + 63) >> 6;                 // dst buckets of 64 nodes
    int chunk = (E + NBLK - 1) / NBLK;
    int ntot = NB * NBLK;                   // hist matrix size
    int nsb = (ntot + 1023) / 1024;         // scan blocks over hmat

    // workspace layout (4-byte elems) — pairs aliases bufH region (build ends before gemm1)
    float* dinv    = (float*)d_ws;                    // n
    float* bufH    = dinv + n;                        // 64n f32 region; holds bf16 hs
    float* bufA    = bufH + (size_t)n * NF;           // 64n f32 region; holds bf16 activations
    int*   counts  = (int*)(bufA + (size_t)n * NF);   // n
    int*   row_ptr = counts + n;                      // n
    int*   col     = row_ptr + n;                     // E
    int*   hmat    = col + E;                         // NB*NBLK
    int*   bptr    = hmat + ntot;                     // NB+1
    int*   bsums   = bptr + NB + 1;                   // <=1024
    int*   pairs   = (int*)bufH;                      // E (build lifetime only)
    ushort_t* hsb  = (ushort_t*)bufH;                 // 64n bf16 (post-build lifetime)
    ushort_t* actb = (ushort_t*)bufA;                 // 64n bf16 layer-1 activations

    // ---- bucket sort by dst (contention-free) ----
    k_histA<<<NBLK, 256, 0, stream>>>(dst, hmat, E, NB, chunk);
    k_scan_a<<<nsb, 256, 0, stream>>>(hmat, hmat, bsums, ntot);
    k_scan_small<<<1, 256, 0, stream>>>(bsums, bsums, nsb);
    k_scan_addb<<<(ntot + 255) / 256, 256, 0, stream>>>(hmat, bsums, bptr, ntot, E);
    k_placeB<<<NBLK, 256, 0, stream>>>(src, dst, hmat, pairs, E, NB, chunk);

    // ---- fused node-level CSR + dinv ----
    k_csr<<<NB, 256, 0, stream>>>(bptr, pairs, row_ptr, counts, dinv, col, n);

    // ---- layer 1: hs = bf16((x @ W1) * dinv) ; pull (+b1, relu) -> bf16 acts ----
    k_gemm<128><<<(n + 63) / 64, 256, 0, stream>>>(x, W1, dinv, hsb, n);
    k_pull<false><<<(n + 15) / 16, 256, 0, stream>>>(hsb, dinv, row_ptr, counts, col, b1,
                                                     Wd, bd, actb, n);

    // ---- layer 2: hs = bf16((acts @ W2) * dinv) ; pull (+b2, relu) + fused decode ----
    k_gemm_bf<<<(n + 63) / 64, 256, 0, stream>>>(actb, W2, dinv, hsb, n);
    k_pull<true><<<(n + 15) / 16, 256, 0, stream>>>(hsb, dinv, row_ptr, counts, col, b2,
                                                    Wd, bd, out, n);
}

// Round 15
// 171.533 us; speedup vs baseline: 1.0698x; 1.0698x over previous
//
#include <hip/hip_runtime.h>

#define NF 64      // hidden width (both layers)
#define NBLK 128   // chunks for the two-pass bucket sort
#define MAXNB 2048 // max buckets supported by LDS histograms (n <= 131072)

typedef unsigned short ushort_t;
typedef __attribute__((ext_vector_type(8))) short short8;   // 8 bf16 = 4 VGPR (MFMA A/B frag)
typedef __attribute__((ext_vector_type(4))) float f32x4;    // MFMA C/D frag

__device__ inline ushort_t f2bf(float f) {               // RNE f32 -> bf16
    unsigned u = __float_as_uint(f);
    return (ushort_t)((u + 0x7fffu + ((u >> 16) & 1u)) >> 16);
}
__device__ inline float bfhi(unsigned x) { return __uint_as_float(x & 0xffff0000u); }
__device__ inline float bflo(unsigned x) { return __uint_as_float(x << 16); }

// =================== scan utilities ===================

__device__ inline int wave_incl_scan(int x, int lane) {
#pragma unroll
    for (int o = 1; o < 64; o <<= 1) { int y = __shfl_up(x, o, 64); if (lane >= o) x += y; }
    return x;
}

// 1024 elements per block (256 threads x 4); in-place safe
__global__ __launch_bounds__(256) void k_scan_a(const int* __restrict__ in, int* __restrict__ out,
                                                int* __restrict__ bsums, int n) {
    int t = threadIdx.x, lane = t & 63, wv = t >> 6;
    int base = blockIdx.x * 1024 + t * 4;
    int v[4]; int s = 0;
#pragma unroll
    for (int k = 0; k < 4; ++k) { int i = base + k; int x = (i < n) ? in[i] : 0; v[k] = s; s += x; }
    int incl = wave_incl_scan(s, lane);
    __shared__ int ws[4];
    if (lane == 63) ws[wv] = incl;
    __syncthreads();
    int wofs = 0;
#pragma unroll
    for (int w = 0; w < 4; ++w) if (w < wv) wofs += ws[w];
    int texcl = wofs + incl - s;
#pragma unroll
    for (int k = 0; k < 4; ++k) { int i = base + k; if (i < n) out[i] = texcl + v[k]; }
    if (t == 255) bsums[blockIdx.x] = wofs + incl;
}

// single-block exclusive scan over up to 2048 entries; in-place safe
__global__ __launch_bounds__(256) void k_scan_small(const int* __restrict__ cnt, int* __restrict__ ptr, int NB) {
    int t = threadIdx.x, lane = t & 63, wv = t >> 6;
    int base = t * 8;
    int local[8]; int s = 0;
#pragma unroll
    for (int k = 0; k < 8; ++k) { int i = base + k; int x = (i < NB) ? cnt[i] : 0; local[k] = s; s += x; }
    int incl = wave_incl_scan(s, lane);
    __shared__ int ws[4];
    if (lane == 63) ws[wv] = incl;
    __syncthreads();
    int wofs = 0;
#pragma unroll
    for (int w = 0; w < 4; ++w) if (w < wv) wofs += ws[w];
    int texcl = wofs + incl - s;
#pragma unroll
    for (int k = 0; k < 8; ++k) { int i = base + k; if (i < NB) ptr[i] = texcl + local[k]; }
}

// add block sums; also emit bucket pointers (bptr[b] = scanned hmat[b*NBLK], bptr[NB] = E)
__global__ __launch_bounds__(256) void k_scan_addb(int* __restrict__ data, const int* __restrict__ bsums,
                                                   int* __restrict__ bptr, int ntot, int E) {
    int i = blockIdx.x * 256 + threadIdx.x;
    if (i < ntot) {
        int v = data[i] + bsums[i >> 10];
        data[i] = v;
        if ((i & (NBLK - 1)) == 0) bptr[i / NBLK] = v;
    }
    if (i == 0) bptr[ntot / NBLK] = E;
}

// =================== contention-free bucket sort (bucket = dst >> 6) ===================

__global__ __launch_bounds__(256) void k_histA(const int* __restrict__ dst, int* __restrict__ hmat,
                                               int E, int NB, int chunk) {
    __shared__ int h[MAXNB];
    int blk = blockIdx.x;
    for (int i = threadIdx.x; i < NB; i += 256) h[i] = 0;
    __syncthreads();
    int beg = blk * chunk, end = beg + chunk; if (end > E) end = E;
    for (int e = beg + threadIdx.x; e < end; e += 256) atomicAdd(&h[dst[e] >> 6], 1);
    __syncthreads();
    for (int i = threadIdx.x; i < NB; i += 256) hmat[i * NBLK + blk] = h[i];
}

__global__ __launch_bounds__(256) void k_placeB(const int* __restrict__ src, const int* __restrict__ dst,
                                                const int* __restrict__ hmat, int* __restrict__ pairs,
                                                int E, int NB, int chunk) {
    __shared__ int cur[MAXNB];
    int blk = blockIdx.x;
    for (int i = threadIdx.x; i < NB; i += 256) cur[i] = hmat[i * NBLK + blk];
    __syncthreads();
    int beg = blk * chunk, end = beg + chunk; if (end > E) end = E;
    for (int e = beg + threadIdx.x; e < end; e += 256) {
        int s = src[e], d = dst[e];
        int off = atomicAdd(&cur[d >> 6], 1);
        pairs[off] = (s << 6) | (d & 63);
    }
}

// =================== fused node-level CSR: hist + 64-scan + row_ptr/cnt/dinv + place ===================
__global__ __launch_bounds__(256) void k_csr(const int* __restrict__ bptr, const int* __restrict__ pairs,
                                             int* __restrict__ row_ptr, int* __restrict__ cnt,
                                             float* __restrict__ dinv, int* __restrict__ col, int n) {
    __shared__ int h[64];
    __shared__ int cur[64];
    int b = blockIdx.x, t = threadIdx.x;
    if (t < 64) h[t] = 0;
    __syncthreads();
    int beg = bptr[b], end = bptr[b + 1];
    for (int j = beg + t; j < end; j += 256) atomicAdd(&h[pairs[j] & 63], 1);
    __syncthreads();
    if (t < 64) {
        int c = h[t];
        int ex = wave_incl_scan(c, t) - c;
        int node = (b << 6) + t;
        if (node < n) {
            row_ptr[node] = beg + ex;
            cnt[node] = c;
            dinv[node] = rsqrtf(1.0f + (float)c);
        }
        cur[t] = beg + ex;
    }
    __syncthreads();
    for (int j = beg + t; j < end; j += 256) {
        int pk = pairs[j];
        int p = atomicAdd(&cur[pk & 63], 1);
        col[p] = pk >> 6;
    }
}

// =================== GEMM1 (f32 in): LDS W + 16-deep k-step — round-13 proven ===================
// hs[n][64](bf16) = (X @ W) * dinv[row].  Block: 64 rows x 64 cols. Thread: 4 rows x 4 cols.
template<int K>
__global__ __launch_bounds__(256, 4) void k_gemm(
    const float* __restrict__ X, const float* __restrict__ W,
    const float* __restrict__ dinv, ushort_t* __restrict__ out, int n)
{
    __shared__ float Ws[K * NF];
    int t = threadIdx.x;
    for (int i = t; i < K * NF / 4; i += 256) ((float4*)Ws)[i] = ((const float4*)W)[i];
    __syncthreads();

    int c0 = (t & 15) * 4;                       // 16 col-groups x 4 cols
    int row0 = blockIdx.x * 64 + (t >> 4) * 4;   // 16 row-groups x 4 rows

    const float* Xr[4];
#pragma unroll
    for (int r = 0; r < 4; ++r) {
        int row = row0 + r; if (row >= n) row = n - 1;   // clamp: dup loads, stores guarded
        Xr[r] = X + (size_t)row * K;
    }

    float4 acc[4];
#pragma unroll
    for (int r = 0; r < 4; ++r) acc[r] = make_float4(0.f, 0.f, 0.f, 0.f);

#pragma unroll 2
    for (int kb = 0; kb < K; kb += 16) {
        float4 xv[4][4];                         // 4 rows x 4 k-chunks, all independent loads
#pragma unroll
        for (int r = 0; r < 4; ++r)
#pragma unroll
            for (int q = 0; q < 4; ++q)
                xv[r][q] = *(const float4*)(Xr[r] + kb + q * 4);

#pragma unroll
        for (int q = 0; q < 4; ++q) {
#pragma unroll
            for (int kk = 0; kk < 4; ++kk) {
                float4 w = *(const float4*)(&Ws[(kb + q * 4 + kk) * NF + c0]);
#pragma unroll
                for (int r = 0; r < 4; ++r) {
                    float xs = ((const float*)&xv[r][q])[kk];
                    acc[r].x = fmaf(xs, w.x, acc[r].x);
                    acc[r].y = fmaf(xs, w.y, acc[r].y);
                    acc[r].z = fmaf(xs, w.z, acc[r].z);
                    acc[r].w = fmaf(xs, w.w, acc[r].w);
                }
            }
        }
    }

#pragma unroll
    for (int r = 0; r < 4; ++r) {
        int row = row0 + r;
        if (row < n) {
            float di = dinv[row];
            ushort4 o;
            o.x = f2bf(acc[r].x * di); o.y = f2bf(acc[r].y * di);
            o.z = f2bf(acc[r].z * di); o.w = f2bf(acc[r].w * di);
            *(ushort4*)(out + (size_t)row * NF + c0) = o;
        }
    }
}

// =================== GEMM2 via MFMA (bf16 x bf16 -> f32) ===================
// hs[n][64](bf16) = (Xb @ W) * dinv[row].  Xb bf16 [n][64], W f32 [64][64].
// Mapping (D = A*B, mfma_f32_16x16x32_bf16):
//   A[i][k] = W[k][cb+i]  (i = lane&15, k = ks*32 + 8*(lane>>4) + jj)
//   B[k][j] = Xb[row0+j][k]  (j = lane&15)  -> lane loads 8 consecutive bf16 = one 16B load
//   D: lane holds out[row0 + (lane&15)][cb + (lane>>4)*4 + r], r=0..3 -> 8B contiguous store
// W pre-swizzled into frag order in LDS (8 KB) -> per-lane frag load = ds_read_b128.
// 2 tiles per wave, all 4 b-frag loads prefetched before compute.
__global__ __launch_bounds__(256) void k_mm2(
    const ushort_t* __restrict__ Xb, const float* __restrict__ W,
    const float* __restrict__ dinv, ushort_t* __restrict__ out, int n)
{
    __shared__ ushort_t wf[8 * 512];             // 8 frags x (64 lanes x 8 bf16)
    int t = threadIdx.x;
    for (int idx = t; idx < 64 * 64; idx += 256) {
        int k = idx >> 6, c = idx & 63;
        int f = ((k >> 5) << 2) | (c >> 4);
        int ln = (c & 15) | (((k >> 3) & 3) << 4);
        wf[f * 512 + ln * 8 + (k & 7)] = f2bf(W[idx]);
    }
    __syncthreads();

    int lane = t & 63, wv = t >> 6;
    short8 af[8];
#pragma unroll
    for (int f = 0; f < 8; ++f)
        af[f] = *(const short8*)(wf + f * 512 + lane * 8);

    int r16 = lane & 15, kg = lane >> 4;
    int tile0 = blockIdx.x * 8 + wv * 2;
    int rowA = tile0 * 16 + r16;
    int rowB = rowA + 16;
    int rA = (rowA < n) ? rowA : (n - 1);        // clamp: dup loads, stores guarded
    int rB = (rowB < n) ? rowB : (n - 1);

    const ushort_t* pA = Xb + (size_t)rA * NF + kg * 8;
    const ushort_t* pB = Xb + (size_t)rB * NF + kg * 8;
    short8 bA0 = *(const short8*)(pA);           // ks=0
    short8 bA1 = *(const short8*)(pA + 32);      // ks=1
    short8 bB0 = *(const short8*)(pB);
    short8 bB1 = *(const short8*)(pB + 32);

    f32x4 z = {0.f, 0.f, 0.f, 0.f};
    f32x4 accA[4], accB[4];
#pragma unroll
    for (int f = 0; f < 4; ++f) {
        accA[f] = __builtin_amdgcn_mfma_f32_16x16x32_bf16(af[f], bA0, z, 0, 0, 0);
        accA[f] = __builtin_amdgcn_mfma_f32_16x16x32_bf16(af[4 + f], bA1, accA[f], 0, 0, 0);
        accB[f] = __builtin_amdgcn_mfma_f32_16x16x32_bf16(af[f], bB0, z, 0, 0, 0);
        accB[f] = __builtin_amdgcn_mfma_f32_16x16x32_bf16(af[4 + f], bB1, accB[f], 0, 0, 0);
    }

    if (rowA < n) {
        float di = dinv[rowA];
#pragma unroll
        for (int f = 0; f < 4; ++f) {
            ushort4 o;
            o.x = f2bf(accA[f][0] * di); o.y = f2bf(accA[f][1] * di);
            o.z = f2bf(accA[f][2] * di); o.w = f2bf(accA[f][3] * di);
            *(ushort4*)(out + (size_t)rowA * NF + f * 16 + kg * 4) = o;
        }
    }
    if (rowB < n) {
        float di = dinv[rowB];
#pragma unroll
        for (int f = 0; f < 4; ++f) {
            ushort4 o;
            o.x = f2bf(accB[f][0] * di); o.y = f2bf(accB[f][1] * di);
            o.z = f2bf(accB[f][2] * di); o.w = f2bf(accB[f][3] * di);
            *(ushort4*)(out + (size_t)rowB * NF + f * 16 + kg * 4) = o;
        }
    }
}

// =================== pull aggregation: one 16-lane group per dst node, bf16 rows ===================
// r = relu( dinv[d] * (hs[d] + sum_{s in N(d)} hs[s]) + bias )
// DECODE=0: write r row as bf16;  DECODE=1: write out[d] = r . Wd + bd (f32 scalar)
template<bool DECODE>
__global__ __launch_bounds__(256) void k_pull(
    const ushort_t* __restrict__ hs, const float* __restrict__ dinv,
    const int* __restrict__ row_ptr, const int* __restrict__ cnt,
    const int* __restrict__ col, const float* __restrict__ bias,
    const float* __restrict__ Wd, const float* __restrict__ bd,
    void* __restrict__ outv, int n)
{
    int d = blockIdx.x * 16 + (threadIdx.x >> 4);
    if (d >= n) return;
    int lt = threadIdx.x & 15;            // lane in group
    int fo = lt << 2;                     // feature offset (4 features/lane)
    int grpbase = threadIdx.x & 48;       // group base lane within wave
    int beg = row_ptr[d], deg = cnt[d];

    // self-loop (bf16 row, 8B/lane)
    uint2 sv = *((const uint2*)(hs + (size_t)d * NF) + lt);
    float4 acc = make_float4(bflo(sv.x), bfhi(sv.x), bflo(sv.y), bfhi(sv.y));

    for (int jb = 0; jb < deg; jb += 16) {
        int m = deg - jb; if (m > 16) m = 16;
        int idx = (lt < m) ? col[beg + jb + lt] : 0;
        uint2 v[16];
#pragma unroll
        for (int u = 0; u < 16; ++u) {
            int kk = (u < m) ? u : (m - 1);                  // clamp: dup loads hit L1
            int s = __shfl(idx, grpbase + kk, 64);
            v[u] = *((const uint2*)(hs + (size_t)s * NF) + lt);
        }
#pragma unroll
        for (int u = 0; u < 16; ++u) {
            if (u < m) {
                acc.x += bflo(v[u].x); acc.y += bfhi(v[u].x);
                acc.z += bflo(v[u].y); acc.w += bfhi(v[u].y);
            }
        }
    }

    float di = dinv[d];
    float4 bv = *(const float4*)(bias + fo);
    float rx = fmaxf(fmaf(acc.x, di, bv.x), 0.0f);
    float ry = fmaxf(fmaf(acc.y, di, bv.y), 0.0f);
    float rz = fmaxf(fmaf(acc.z, di, bv.z), 0.0f);
    float rw = fmaxf(fmaf(acc.w, di, bv.w), 0.0f);

    if (DECODE) {
        float4 wv = *(const float4*)(Wd + fo);
        float vsum = rx * wv.x + ry * wv.y + rz * wv.z + rw * wv.w;
#pragma unroll
        for (int o = 1; o < 16; o <<= 1) vsum += __shfl_xor(vsum, o, 64);
        if (lt == 0) ((float*)outv)[d] = vsum + bd[0];
    } else {
        ushort4 o;
        o.x = f2bf(rx); o.y = f2bf(ry); o.z = f2bf(rz); o.w = f2bf(rw);
        *(ushort4*)((ushort_t*)outv + (size_t)d * NF + fo) = o;
    }
}

extern "C" void kernel_launch(void* const* d_in, const int* in_sizes, int n_in,
                              void* d_out, int out_size, void* d_ws, size_t ws_size,
                              hipStream_t stream) {
    const float* x  = (const float*)d_in[0];
    const int*   ei = (const int*)d_in[1];
    const float* W1 = (const float*)d_in[2];
    const float* b1 = (const float*)d_in[3];
    const float* W2 = (const float*)d_in[4];
    const float* b2 = (const float*)d_in[5];
    const float* Wd = (const float*)d_in[6];
    const float* bd = (const float*)d_in[7];
    float* out = (float*)d_out;

    int n = in_sizes[0] / 128;
    int E = in_sizes[1] / 2;
    const int* src = ei;
    const int* dst = ei + E;

    int NB = (n + 63) >> 6;                 // dst buckets of 64 nodes
    int chunk = (E + NBLK - 1) / NBLK;
    int ntot = NB * NBLK;                   // hist matrix size
    int nsb = (ntot + 1023) / 1024;         // scan blocks over hmat
    int ntiles = (n + 15) / 16;             // 16-row MFMA tiles

    // workspace layout (4-byte elems) — pairs aliases bufH region (build ends before gemm1)
    float* dinv    = (float*)d_ws;                    // n
    float* bufH    = dinv + n;                        // 64n f32 region; holds bf16 hs
    float* bufA    = bufH + (size_t)n * NF;           // 64n f32 region; holds bf16 activations
    int*   counts  = (int*)(bufA + (size_t)n * NF);   // n
    int*   row_ptr = counts + n;                      // n
    int*   col     = row_ptr + n;                     // E
    int*   hmat    = col + E;                         // NB*NBLK
    int*   bptr    = hmat + ntot;                     // NB+1
    int*   bsums   = bptr + NB + 1;                   // <=1024
    int*   pairs   = (int*)bufH;                      // E (build lifetime only)
    ushort_t* hsb  = (ushort_t*)bufH;                 // 64n bf16 (post-build lifetime)
    ushort_t* actb = (ushort_t*)bufA;                 // 64n bf16 layer-1 activations

    // ---- bucket sort by dst (contention-free) ----
    k_histA<<<NBLK, 256, 0, stream>>>(dst, hmat, E, NB, chunk);
    k_scan_a<<<nsb, 256, 0, stream>>>(hmat, hmat, bsums, ntot);
    k_scan_small<<<1, 256, 0, stream>>>(bsums, bsums, nsb);
    k_scan_addb<<<(ntot + 255) / 256, 256, 0, stream>>>(hmat, bsums, bptr, ntot, E);
    k_placeB<<<NBLK, 256, 0, stream>>>(src, dst, hmat, pairs, E, NB, chunk);

    // ---- fused node-level CSR + dinv ----
    k_csr<<<NB, 256, 0, stream>>>(bptr, pairs, row_ptr, counts, dinv, col, n);

    // ---- layer 1: hs = bf16((x @ W1) * dinv) ; pull (+b1, relu) -> bf16 acts ----
    k_gemm<128><<<(n + 63) / 64, 256, 0, stream>>>(x, W1, dinv, hsb, n);
    k_pull<false><<<(n + 15) / 16, 256, 0, stream>>>(hsb, dinv, row_ptr, counts, col, b1,
                                                     Wd, bd, actb, n);

    // ---- layer 2 (MFMA): hs = bf16((acts @ W2) * dinv) ; pull (+b2, relu) + fused decode ----
    k_mm2<<<(ntiles + 7) / 8, 256, 0, stream>>>(actb, W2, dinv, hsb, n);
    k_pull<true><<<(n + 15) / 16, 256, 0, stream>>>(hsb, dinv, row_ptr, counts, col, b2,
                                                    Wd, bd, out, n);
}

// Round 16
// 155.404 us; speedup vs baseline: 1.1808x; 1.1038x over previous
//
#include <hip/hip_runtime.h>

#define NF 64      // hidden width (both layers)
#define NBLK 128   // chunks for the two-pass bucket sort
#define MAXNB 2048 // max buckets supported by LDS histograms (n <= 131072)

typedef unsigned short ushort_t;
typedef __attribute__((ext_vector_type(8))) short short8;   // 8 bf16 = 4 VGPR (MFMA A/B frag)
typedef __attribute__((ext_vector_type(4))) float f32x4;    // MFMA C/D frag

__device__ inline ushort_t f2bf(float f) {               // RNE f32 -> bf16
    unsigned u = __float_as_uint(f);
    return (ushort_t)((u + 0x7fffu + ((u >> 16) & 1u)) >> 16);
}
__device__ inline float bfhi(unsigned x) { return __uint_as_float(x & 0xffff0000u); }
__device__ inline float bflo(unsigned x) { return __uint_as_float(x << 16); }

#define PACK8(b, ua, ub) \
    b[0] = (short)f2bf(ua.x); b[1] = (short)f2bf(ua.y); \
    b[2] = (short)f2bf(ua.z); b[3] = (short)f2bf(ua.w); \
    b[4] = (short)f2bf(ub.x); b[5] = (short)f2bf(ub.y); \
    b[6] = (short)f2bf(ub.z); b[7] = (short)f2bf(ub.w);

// =================== scan utilities ===================

__device__ inline int wave_incl_scan(int x, int lane) {
#pragma unroll
    for (int o = 1; o < 64; o <<= 1) { int y = __shfl_up(x, o, 64); if (lane >= o) x += y; }
    return x;
}

// 1024 elements per block (256 threads x 4); in-place safe
__global__ __launch_bounds__(256) void k_scan_a(const int* __restrict__ in, int* __restrict__ out,
                                                int* __restrict__ bsums, int n) {
    int t = threadIdx.x, lane = t & 63, wv = t >> 6;
    int base = blockIdx.x * 1024 + t * 4;
    int v[4]; int s = 0;
#pragma unroll
    for (int k = 0; k < 4; ++k) { int i = base + k; int x = (i < n) ? in[i] : 0; v[k] = s; s += x; }
    int incl = wave_incl_scan(s, lane);
    __shared__ int ws[4];
    if (lane == 63) ws[wv] = incl;
    __syncthreads();
    int wofs = 0;
#pragma unroll
    for (int w = 0; w < 4; ++w) if (w < wv) wofs += ws[w];
    int texcl = wofs + incl - s;
#pragma unroll
    for (int k = 0; k < 4; ++k) { int i = base + k; if (i < n) out[i] = texcl + v[k]; }
    if (t == 255) bsums[blockIdx.x] = wofs + incl;
}

// single-block exclusive scan over up to 2048 entries; in-place safe
__global__ __launch_bounds__(256) void k_scan_small(const int* __restrict__ cnt, int* __restrict__ ptr, int NB) {
    int t = threadIdx.x, lane = t & 63, wv = t >> 6;
    int base = t * 8;
    int local[8]; int s = 0;
#pragma unroll
    for (int k = 0; k < 8; ++k) { int i = base + k; int x = (i < NB) ? cnt[i] : 0; local[k] = s; s += x; }
    int incl = wave_incl_scan(s, lane);
    __shared__ int ws[4];
    if (lane == 63) ws[wv] = incl;
    __syncthreads();
    int wofs = 0;
#pragma unroll
    for (int w = 0; w < 4; ++w) if (w < wv) wofs += ws[w];
    int texcl = wofs + incl - s;
#pragma unroll
    for (int k = 0; k < 8; ++k) { int i = base + k; if (i < NB) ptr[i] = texcl + local[k]; }
}

// add block sums; also emit bucket pointers (bptr[b] = scanned hmat[b*NBLK], bptr[NB] = E)
__global__ __launch_bounds__(256) void k_scan_addb(int* __restrict__ data, const int* __restrict__ bsums,
                                                   int* __restrict__ bptr, int ntot, int E) {
    int i = blockIdx.x * 256 + threadIdx.x;
    if (i < ntot) {
        int v = data[i] + bsums[i >> 10];
        data[i] = v;
        if ((i & (NBLK - 1)) == 0) bptr[i / NBLK] = v;
    }
    if (i == 0) bptr[ntot / NBLK] = E;
}

// =================== contention-free bucket sort (bucket = dst >> 6) ===================

__global__ __launch_bounds__(256) void k_histA(const int* __restrict__ dst, int* __restrict__ hmat,
                                               int E, int NB, int chunk) {
    __shared__ int h[MAXNB];
    int blk = blockIdx.x;
    for (int i = threadIdx.x; i < NB; i += 256) h[i] = 0;
    __syncthreads();
    int beg = blk * chunk, end = beg + chunk; if (end > E) end = E;
    for (int e = beg + threadIdx.x; e < end; e += 256) atomicAdd(&h[dst[e] >> 6], 1);
    __syncthreads();
    for (int i = threadIdx.x; i < NB; i += 256) hmat[i * NBLK + blk] = h[i];
}

__global__ __launch_bounds__(256) void k_placeB(const int* __restrict__ src, const int* __restrict__ dst,
                                                const int* __restrict__ hmat, int* __restrict__ pairs,
                                                int E, int NB, int chunk) {
    __shared__ int cur[MAXNB];
    int blk = blockIdx.x;
    for (int i = threadIdx.x; i < NB; i += 256) cur[i] = hmat[i * NBLK + blk];
    __syncthreads();
    int beg = blk * chunk, end = beg + chunk; if (end > E) end = E;
    for (int e = beg + threadIdx.x; e < end; e += 256) {
        int s = src[e], d = dst[e];
        int off = atomicAdd(&cur[d >> 6], 1);
        pairs[off] = (s << 6) | (d & 63);
    }
}

// =================== fused node-level CSR: hist + 64-scan + row_ptr/cnt/dinv + place ===================
__global__ __launch_bounds__(256) void k_csr(const int* __restrict__ bptr, const int* __restrict__ pairs,
                                             int* __restrict__ row_ptr, int* __restrict__ cnt,
                                             float* __restrict__ dinv, int* __restrict__ col, int n) {
    __shared__ int h[64];
    __shared__ int cur[64];
    int b = blockIdx.x, t = threadIdx.x;
    if (t < 64) h[t] = 0;
    __syncthreads();
    int beg = bptr[b], end = bptr[b + 1];
    for (int j = beg + t; j < end; j += 256) atomicAdd(&h[pairs[j] & 63], 1);
    __syncthreads();
    if (t < 64) {
        int c = h[t];
        int ex = wave_incl_scan(c, t) - c;
        int node = (b << 6) + t;
        if (node < n) {
            row_ptr[node] = beg + ex;
            cnt[node] = c;
            dinv[node] = rsqrtf(1.0f + (float)c);
        }
        cur[t] = beg + ex;
    }
    __syncthreads();
    for (int j = beg + t; j < end; j += 256) {
        int pk = pairs[j];
        int p = atomicAdd(&cur[pk & 63], 1);
        col[p] = pk >> 6;
    }
}

// =================== GEMM1 via MFMA (f32 -> bf16 in-register, K=128) ===================
// hs[n][64](bf16) = (X @ W) * dinv[row].  X f32 [n][128], W f32 [128][64].
// Same hardware-validated mapping as k_mm2, extended to 4 k-slices:
//   A[i][k] = W[k][f16grp*16+i], lane=(i)|(kg<<4), elem jj -> k = ks*32 + kg*8 + jj
//   B[k][j] = bf16(X[tile*16+j][k]), lane j loads 8 consecutive f32 at kg*8 + ks*32
//   D: lane holds out[tile*16 + (lane&15)][f*16 + kg*4 + r], r=0..3 -> 8B store
__global__ __launch_bounds__(256) void k_mm1(
    const float* __restrict__ X, const float* __restrict__ W,
    const float* __restrict__ dinv, ushort_t* __restrict__ out, int n)
{
    __shared__ ushort_t wf[16 * 512];            // 16 KB: 16 frags x (64 lanes x 8 bf16)
    int t = threadIdx.x;
    for (int idx = t; idx < 128 * 64; idx += 256) {
        int k = idx >> 6, c = idx & 63;
        int f = ((k >> 5) << 2) | (c >> 4);
        int ln = (c & 15) | (((k >> 3) & 3) << 4);
        wf[f * 512 + ln * 8 + (k & 7)] = f2bf(W[idx]);
    }
    __syncthreads();

    int lane = t & 63, wv = t >> 6;
    int r16 = lane & 15, kg = lane >> 4;
    int tile = blockIdx.x * 4 + wv;              // one 16-row tile per wave
    int row = tile * 16 + r16;
    int r = (row < n) ? row : (n - 1);           // clamp: dup loads, stores guarded
    const float* pX = X + (size_t)r * 128 + kg * 8;

    // prefetch all 8 x-chunks (4 k-slices x 32 B) for MLP
    float4 u0a = *(const float4*)(pX + 0),   u0b = *(const float4*)(pX + 4);
    float4 u1a = *(const float4*)(pX + 32),  u1b = *(const float4*)(pX + 36);
    float4 u2a = *(const float4*)(pX + 64),  u2b = *(const float4*)(pX + 68);
    float4 u3a = *(const float4*)(pX + 96),  u3b = *(const float4*)(pX + 100);

    short8 b0, b1, b2, b3;
    PACK8(b0, u0a, u0b); PACK8(b1, u1a, u1b);
    PACK8(b2, u2a, u2b); PACK8(b3, u3a, u3b);

    short8 a0[4], a1[4], a2[4], a3[4];
#pragma unroll
    for (int f = 0; f < 4; ++f) {
        a0[f] = *(const short8*)(wf + (0 + f) * 512 + lane * 8);
        a1[f] = *(const short8*)(wf + (4 + f) * 512 + lane * 8);
        a2[f] = *(const short8*)(wf + (8 + f) * 512 + lane * 8);
        a3[f] = *(const short8*)(wf + (12 + f) * 512 + lane * 8);
    }

    f32x4 z = {0.f, 0.f, 0.f, 0.f};
    f32x4 acc[4];
#pragma unroll
    for (int f = 0; f < 4; ++f)
        acc[f] = __builtin_amdgcn_mfma_f32_16x16x32_bf16(a0[f], b0, z, 0, 0, 0);
#pragma unroll
    for (int f = 0; f < 4; ++f)
        acc[f] = __builtin_amdgcn_mfma_f32_16x16x32_bf16(a1[f], b1, acc[f], 0, 0, 0);
#pragma unroll
    for (int f = 0; f < 4; ++f)
        acc[f] = __builtin_amdgcn_mfma_f32_16x16x32_bf16(a2[f], b2, acc[f], 0, 0, 0);
#pragma unroll
    for (int f = 0; f < 4; ++f)
        acc[f] = __builtin_amdgcn_mfma_f32_16x16x32_bf16(a3[f], b3, acc[f], 0, 0, 0);

    if (row < n) {
        float di = dinv[row];
#pragma unroll
        for (int f = 0; f < 4; ++f) {
            ushort4 o;
            o.x = f2bf(acc[f][0] * di); o.y = f2bf(acc[f][1] * di);
            o.z = f2bf(acc[f][2] * di); o.w = f2bf(acc[f][3] * di);
            *(ushort4*)(out + (size_t)row * NF + f * 16 + kg * 4) = o;
        }
    }
}

// =================== GEMM2 via MFMA (bf16 x bf16 -> f32) — round-15 validated ===================
__global__ __launch_bounds__(256) void k_mm2(
    const ushort_t* __restrict__ Xb, const float* __restrict__ W,
    const float* __restrict__ dinv, ushort_t* __restrict__ out, int n)
{
    __shared__ ushort_t wf[8 * 512];             // 8 frags x (64 lanes x 8 bf16)
    int t = threadIdx.x;
    for (int idx = t; idx < 64 * 64; idx += 256) {
        int k = idx >> 6, c = idx & 63;
        int f = ((k >> 5) << 2) | (c >> 4);
        int ln = (c & 15) | (((k >> 3) & 3) << 4);
        wf[f * 512 + ln * 8 + (k & 7)] = f2bf(W[idx]);
    }
    __syncthreads();

    int lane = t & 63, wv = t >> 6;
    short8 af[8];
#pragma unroll
    for (int f = 0; f < 8; ++f)
        af[f] = *(const short8*)(wf + f * 512 + lane * 8);

    int r16 = lane & 15, kg = lane >> 4;
    int tile0 = blockIdx.x * 8 + wv * 2;
    int rowA = tile0 * 16 + r16;
    int rowB = rowA + 16;
    int rA = (rowA < n) ? rowA : (n - 1);        // clamp: dup loads, stores guarded
    int rB = (rowB < n) ? rowB : (n - 1);

    const ushort_t* pA = Xb + (size_t)rA * NF + kg * 8;
    const ushort_t* pB = Xb + (size_t)rB * NF + kg * 8;
    short8 bA0 = *(const short8*)(pA);           // ks=0
    short8 bA1 = *(const short8*)(pA + 32);      // ks=1
    short8 bB0 = *(const short8*)(pB);
    short8 bB1 = *(const short8*)(pB + 32);

    f32x4 z = {0.f, 0.f, 0.f, 0.f};
    f32x4 accA[4], accB[4];
#pragma unroll
    for (int f = 0; f < 4; ++f) {
        accA[f] = __builtin_amdgcn_mfma_f32_16x16x32_bf16(af[f], bA0, z, 0, 0, 0);
        accA[f] = __builtin_amdgcn_mfma_f32_16x16x32_bf16(af[4 + f], bA1, accA[f], 0, 0, 0);
        accB[f] = __builtin_amdgcn_mfma_f32_16x16x32_bf16(af[f], bB0, z, 0, 0, 0);
        accB[f] = __builtin_amdgcn_mfma_f32_16x16x32_bf16(af[4 + f], bB1, accB[f], 0, 0, 0);
    }

    if (rowA < n) {
        float di = dinv[rowA];
#pragma unroll
        for (int f = 0; f < 4; ++f) {
            ushort4 o;
            o.x = f2bf(accA[f][0] * di); o.y = f2bf(accA[f][1] * di);
            o.z = f2bf(accA[f][2] * di); o.w = f2bf(accA[f][3] * di);
            *(ushort4*)(out + (size_t)rowA * NF + f * 16 + kg * 4) = o;
        }
    }
    if (rowB < n) {
        float di = dinv[rowB];
#pragma unroll
        for (int f = 0; f < 4; ++f) {
            ushort4 o;
            o.x = f2bf(accB[f][0] * di); o.y = f2bf(accB[f][1] * di);
            o.z = f2bf(accB[f][2] * di); o.w = f2bf(accB[f][3] * di);
            *(ushort4*)(out + (size_t)rowB * NF + f * 16 + kg * 4) = o;
        }
    }
}

// =================== pull aggregation: one 16-lane group per dst node, bf16 rows ===================
// r = relu( dinv[d] * (hs[d] + sum_{s in N(d)} hs[s]) + bias )
// DECODE=0: write r row as bf16;  DECODE=1: write out[d] = r . Wd + bd (f32 scalar)
template<bool DECODE>
__global__ __launch_bounds__(256) void k_pull(
    const ushort_t* __restrict__ hs, const float* __restrict__ dinv,
    const int* __restrict__ row_ptr, const int* __restrict__ cnt,
    const int* __restrict__ col, const float* __restrict__ bias,
    const float* __restrict__ Wd, const float* __restrict__ bd,
    void* __restrict__ outv, int n)
{
    int d = blockIdx.x * 16 + (threadIdx.x >> 4);
    if (d >= n) return;
    int lt = threadIdx.x & 15;            // lane in group
    int fo = lt << 2;                     // feature offset (4 features/lane)
    int grpbase = threadIdx.x & 48;       // group base lane within wave
    int beg = row_ptr[d], deg = cnt[d];

    // self-loop (bf16 row, 8B/lane)
    uint2 sv = *((const uint2*)(hs + (size_t)d * NF) + lt);
    float4 acc = make_float4(bflo(sv.x), bfhi(sv.x), bflo(sv.y), bfhi(sv.y));

    for (int jb = 0; jb < deg; jb += 16) {
        int m = deg - jb; if (m > 16) m = 16;
        int idx = (lt < m) ? col[beg + jb + lt] : 0;
        uint2 v[16];
#pragma unroll
        for (int u = 0; u < 16; ++u) {
            int kk = (u < m) ? u : (m - 1);                  // clamp: dup loads hit L1
            int s = __shfl(idx, grpbase + kk, 64);
            v[u] = *((const uint2*)(hs + (size_t)s * NF) + lt);
        }
#pragma unroll
        for (int u = 0; u < 16; ++u) {
            if (u < m) {
                acc.x += bflo(v[u].x); acc.y += bfhi(v[u].x);
                acc.z += bflo(v[u].y); acc.w += bfhi(v[u].y);
            }
        }
    }

    float di = dinv[d];
    float4 bv = *(const float4*)(bias + fo);
    float rx = fmaxf(fmaf(acc.x, di, bv.x), 0.0f);
    float ry = fmaxf(fmaf(acc.y, di, bv.y), 0.0f);
    float rz = fmaxf(fmaf(acc.z, di, bv.z), 0.0f);
    float rw = fmaxf(fmaf(acc.w, di, bv.w), 0.0f);

    if (DECODE) {
        float4 wv = *(const float4*)(Wd + fo);
        float vsum = rx * wv.x + ry * wv.y + rz * wv.z + rw * wv.w;
#pragma unroll
        for (int o = 1; o < 16; o <<= 1) vsum += __shfl_xor(vsum, o, 64);
        if (lt == 0) ((float*)outv)[d] = vsum + bd[0];
    } else {
        ushort4 o;
        o.x = f2bf(rx); o.y = f2bf(ry); o.z = f2bf(rz); o.w = f2bf(rw);
        *(ushort4*)((ushort_t*)outv + (size_t)d * NF + fo) = o;
    }
}

extern "C" void kernel_launch(void* const* d_in, const int* in_sizes, int n_in,
                              void* d_out, int out_size, void* d_ws, size_t ws_size,
                              hipStream_t stream) {
    const float* x  = (const float*)d_in[0];
    const int*   ei = (const int*)d_in[1];
    const float* W1 = (const float*)d_in[2];
    const float* b1 = (const float*)d_in[3];
    const float* W2 = (const float*)d_in[4];
    const float* b2 = (const float*)d_in[5];
    const float* Wd = (const float*)d_in[6];
    const float* bd = (const float*)d_in[7];
    float* out = (float*)d_out;

    int n = in_sizes[0] / 128;
    int E = in_sizes[1] / 2;
    const int* src = ei;
    const int* dst = ei + E;

    int NB = (n + 63) >> 6;                 // dst buckets of 64 nodes
    int chunk = (E + NBLK - 1) / NBLK;
    int ntot = NB * NBLK;                   // hist matrix size
    int nsb = (ntot + 1023) / 1024;         // scan blocks over hmat
    int ntiles = (n + 15) / 16;             // 16-row MFMA tiles

    // workspace layout (4-byte elems) — pairs aliases bufH region (build ends before gemm1)
    float* dinv    = (float*)d_ws;                    // n
    float* bufH    = dinv + n;                        // 64n f32 region; holds bf16 hs
    float* bufA    = bufH + (size_t)n * NF;           // 64n f32 region; holds bf16 activations
    int*   counts  = (int*)(bufA + (size_t)n * NF);   // n
    int*   row_ptr = counts + n;                      // n
    int*   col     = row_ptr + n;                     // E
    int*   hmat    = col + E;                         // NB*NBLK
    int*   bptr    = hmat + ntot;                     // NB+1
    int*   bsums   = bptr + NB + 1;                   // <=1024
    int*   pairs   = (int*)bufH;                      // E (build lifetime only)
    ushort_t* hsb  = (ushort_t*)bufH;                 // 64n bf16 (post-build lifetime)
    ushort_t* actb = (ushort_t*)bufA;                 // 64n bf16 layer-1 activations

    // ---- bucket sort by dst (contention-free) ----
    k_histA<<<NBLK, 256, 0, stream>>>(dst, hmat, E, NB, chunk);
    k_scan_a<<<nsb, 256, 0, stream>>>(hmat, hmat, bsums, ntot);
    k_scan_small<<<1, 256, 0, stream>>>(bsums, bsums, nsb);
    k_scan_addb<<<(ntot + 255) / 256, 256, 0, stream>>>(hmat, bsums, bptr, ntot, E);
    k_placeB<<<NBLK, 256, 0, stream>>>(src, dst, hmat, pairs, E, NB, chunk);

    // ---- fused node-level CSR + dinv ----
    k_csr<<<NB, 256, 0, stream>>>(bptr, pairs, row_ptr, counts, dinv, col, n);

    // ---- layer 1 (MFMA): hs = bf16((x @ W1) * dinv) ; pull (+b1, relu) -> bf16 acts ----
    k_mm1<<<(ntiles + 3) / 4, 256, 0, stream>>>(x, W1, dinv, hsb, n);
    k_pull<false><<<(n + 15) / 16, 256, 0, stream>>>(hsb, dinv, row_ptr, counts, col, b1,
                                                     Wd, bd, actb, n);

    // ---- layer 2 (MFMA): hs = bf16((acts @ W2) * dinv) ; pull (+b2, relu) + fused decode ----
    k_mm2<<<(ntiles + 7) / 8, 256, 0, stream>>>(actb, W2, dinv, hsb, n);
    k_pull<true><<<(n + 15) / 16, 256, 0, stream>>>(hsb, dinv, row_ptr, counts, col, b2,
                                                    Wd, bd, out, n);
}